// Round 1
// baseline (668.079 us; speedup 1.0000x reference)
//
#include <hip/hip_runtime.h>
#include <math.h>

// MemoryUnit: fn=l2norm(feature), mn=l2norm(memory), S=fn.mn^T -> softmax ->
// hardshrink(0.0005) -> softmax -> w ; mem_feat = w @ memory.
// Strategy: raw-dot GEMMs in bf16 MFMA, normalize by (1/|f|)(1/|m|) at softmax time.

#define D_DIM 32768
#define B_DIM 256
#define M_DIM 2000
#define M_PAD 2048
#define LAM 0.0005f

typedef __attribute__((ext_vector_type(8))) short bf16x8;   // 8 bf16 = 4 VGPR
typedef __attribute__((ext_vector_type(8))) short s8vec;    // 16B ushort-ish vector
typedef __attribute__((ext_vector_type(4))) float f32x4;

__device__ __forceinline__ unsigned short f2bf(float f) {
  union { float f; unsigned u; } v; v.f = f;
  unsigned r = v.u + 0x7FFFu + ((v.u >> 16) & 1u);  // RNE
  return (unsigned short)(r >> 16);
}

// ---------------- zero S ----------------
__global__ __launch_bounds__(256) void zero_kernel(float* __restrict__ p, int n) {
  int i = blockIdx.x * 256 + threadIdx.x;
  if (i < n) p[i] = 0.f;
}

// ---------------- row 1/max(||x||,eps) ----------------
__global__ __launch_bounds__(256) void rownorm_kernel(const float* __restrict__ src,
                                                      float* __restrict__ rn) {
  const size_t row = blockIdx.x;
  const float4* p = (const float4*)(src + row * (size_t)D_DIM);
  float s = 0.f;
  for (int i = threadIdx.x; i < D_DIM / 4; i += 256) {
    float4 v = p[i];
    s = fmaf(v.x, v.x, s); s = fmaf(v.y, v.y, s);
    s = fmaf(v.z, v.z, s); s = fmaf(v.w, v.w, s);
  }
  #pragma unroll
  for (int off = 32; off > 0; off >>= 1) s += __shfl_down(s, off, 64);
  __shared__ float partial[4];
  if ((threadIdx.x & 63) == 0) partial[threadIdx.x >> 6] = s;
  __syncthreads();
  if (threadIdx.x == 0) {
    float t = partial[0] + partial[1] + partial[2] + partial[3];
    rn[row] = 1.0f / fmaxf(sqrtf(t), 1e-12f);
  }
}

// ---------------- GEMM1: S[b][m] += feature[b][:] . memory[m][:] ----------------
// BM=256 (all rows), BN=64, BK=32, split-K=16 (grid 32x16). LDS stride 40 ushorts
// (80 B -> bank step 20, no 16-way aliasing; 16B-aligned for ds_read_b128).
#define G1_LDA 40
__global__ __launch_bounds__(256) void gemm1_kernel(const float* __restrict__ A,
                                                    const float* __restrict__ Bm,
                                                    float* __restrict__ S) {
  __shared__ __align__(16) unsigned short Asm[256 * G1_LDA];  // 20 KB
  __shared__ __align__(16) unsigned short Bsm[64 * G1_LDA];   // 5 KB
  const int t = threadIdx.x;
  const int n0 = blockIdx.x * 64;
  const int kbase = blockIdx.y * 2048;
  const int wid = t >> 6, lane = t & 63;
  const int lr = lane & 15, kq = lane >> 4;

  f32x4 acc[4][4] = {};

  const int ra = t >> 3;        // 0..31
  const int c4 = (t & 7) * 4;   // float4 col within 32-wide K slab

  for (int kk = 0; kk < 2048; kk += 32) {
    const int kg = kbase + kk + c4;
    __syncthreads();
    #pragma unroll
    for (int i = 0; i < 8; i++) {            // A: 256 rows x 32 k
      const int r = ra + 32 * i;
      const float4 v = *(const float4*)(A + (size_t)r * D_DIM + kg);
      ushort4 b; b.x = f2bf(v.x); b.y = f2bf(v.y); b.z = f2bf(v.z); b.w = f2bf(v.w);
      *(ushort4*)&Asm[r * G1_LDA + c4] = b;
    }
    #pragma unroll
    for (int i = 0; i < 2; i++) {            // B: 64 rows x 32 k, predicated m<2000
      const int r = ra + 32 * i;
      const int gm = n0 + r;
      float4 v = make_float4(0.f, 0.f, 0.f, 0.f);
      if (gm < M_DIM) v = *(const float4*)(Bm + (size_t)gm * D_DIM + kg);
      ushort4 b; b.x = f2bf(v.x); b.y = f2bf(v.y); b.z = f2bf(v.z); b.w = f2bf(v.w);
      *(ushort4*)&Bsm[r * G1_LDA + c4] = b;
    }
    __syncthreads();
    bf16x8 bfr[4];
    #pragma unroll
    for (int ni = 0; ni < 4; ni++)
      bfr[ni] = *(const bf16x8*)&Bsm[(ni * 16 + lr) * G1_LDA + kq * 8];
    #pragma unroll
    for (int mi = 0; mi < 4; mi++) {
      const bf16x8 af = *(const bf16x8*)&Asm[(wid * 64 + mi * 16 + lr) * G1_LDA + kq * 8];
      #pragma unroll
      for (int ni = 0; ni < 4; ni++)
        acc[mi][ni] = __builtin_amdgcn_mfma_f32_16x16x32_bf16(af, bfr[ni], acc[mi][ni], 0, 0, 0);
    }
  }
  // epilogue: split-K accumulate. C/D layout: col=lane&15, row=(lane>>4)*4+j.
  #pragma unroll
  for (int mi = 0; mi < 4; mi++) {
    const int row0 = wid * 64 + mi * 16 + kq * 4;
    #pragma unroll
    for (int ni = 0; ni < 4; ni++) {
      const int col = n0 + ni * 16 + lr;   // < 2048, S padded -> safe
      #pragma unroll
      for (int j = 0; j < 4; j++)
        atomicAdd(&S[(size_t)(row0 + j) * M_PAD + col], acc[mi][ni][j]);
    }
  }
}

// ---------------- softmax -> hardshrink -> softmax ----------------
__device__ __forceinline__ float block_reduce(float x, bool is_max, float* red,
                                              int wid, int lane) {
  #pragma unroll
  for (int off = 32; off > 0; off >>= 1) {
    float o = __shfl_down(x, off, 64);
    x = is_max ? fmaxf(x, o) : (x + o);
  }
  __syncthreads();                 // protect previous use of red
  if (lane == 0) red[wid] = x;
  __syncthreads();
  return is_max ? fmaxf(fmaxf(red[0], red[1]), fmaxf(red[2], red[3]))
                : (red[0] + red[1] + red[2] + red[3]);
}

__global__ __launch_bounds__(256) void softmax_kernel(const float* __restrict__ S,
                                                      const float* __restrict__ rnf,
                                                      const float* __restrict__ rnm,
                                                      float* __restrict__ wout,
                                                      unsigned short* __restrict__ wbf) {
  const int b = blockIdx.x;
  const int t = threadIdx.x;
  const int wid = t >> 6, lane = t & 63;
  const float sf = rnf[b];
  __shared__ float red[4];

  float v[8];
  #pragma unroll
  for (int i = 0; i < 8; i++) {
    const int m = t + 256 * i;
    v[i] = (m < M_DIM) ? S[(size_t)b * M_PAD + m] * (sf * rnm[m]) : -INFINITY;
  }
  float mx = v[0];
  #pragma unroll
  for (int i = 1; i < 8; i++) mx = fmaxf(mx, v[i]);
  mx = block_reduce(mx, true, red, wid, lane);

  float e[8]; float sum = 0.f;
  #pragma unroll
  for (int i = 0; i < 8; i++) { e[i] = expf(v[i] - mx); sum += e[i]; }  // -inf -> 0
  sum = block_reduce(sum, false, red, wid, lane);
  const float inv = 1.f / sum;

  float s2[8];
  #pragma unroll
  for (int i = 0; i < 8; i++) {
    float w1 = e[i] * inv;
    s2[i] = (w1 > LAM) ? w1 : 0.f;           // hard shrink (w1 >= 0)
  }
  float mx2 = 0.f;                           // all s2 >= 0
  #pragma unroll
  for (int i = 0; i < 8; i++) mx2 = fmaxf(mx2, s2[i]);
  mx2 = block_reduce(mx2, true, red, wid, lane);

  float e2[8]; float sum2 = 0.f;
  #pragma unroll
  for (int i = 0; i < 8; i++) {
    const int m = t + 256 * i;
    e2[i] = (m < M_DIM) ? expf(s2[i] - mx2) : 0.f;  // zeros ARE valid entries
    sum2 += e2[i];
  }
  sum2 = block_reduce(sum2, false, red, wid, lane);
  const float inv2 = 1.f / sum2;

  #pragma unroll
  for (int i = 0; i < 8; i++) {
    const int m = t + 256 * i;
    const float w2 = e2[i] * inv2;
    if (m < M_DIM) wout[(size_t)b * M_DIM + m] = w2;
    wbf[(size_t)b * M_PAD + m] = f2bf(w2);   // padded cols get exact 0
  }
}

// ---------------- GEMM2: C[b][n] = sum_k W[b][k] * memory[k][n] ----------------
// BM=256 (all rows -> memory streamed once), BN=64, BK=32, grid 512 n-tiles.
// B staged TRANSPOSED into LDS ([n][k], k-contig) so B-frags are ds_read_b128.
#define G2_LDB 40
__global__ __launch_bounds__(256) void gemm2_kernel(const unsigned short* __restrict__ W,
                                                    const float* __restrict__ Bm,
                                                    float* __restrict__ C) {
  __shared__ __align__(16) unsigned short Wsm[256 * G2_LDB];  // 20 KB
  __shared__ __align__(16) unsigned short Bt[64 * G2_LDB];    // 5 KB
  const int t = threadIdx.x;
  const int n0 = blockIdx.x * 64;
  const int wid = t >> 6, lane = t & 63;
  const int lr = lane & 15, kq = lane >> 4;
  f32x4 acc[4][4] = {};

  const int wr = t >> 2;          // 0..63: W stage row base
  const int wc8 = (t & 3) * 8;    // ushort col (8-wide chunks)
  const int bn = t & 63;          // B stage: col n
  const int kgq = t >> 6;         // 0..3: k quad group

  for (int k0 = 0; k0 < M_PAD; k0 += 32) {
    __syncthreads();
    #pragma unroll
    for (int i = 0; i < 4; i++) {  // W: 256 rows x 32 k (bf16 already)
      const int r = wr + 64 * i;
      const s8vec v = *(const s8vec*)(W + (size_t)r * M_PAD + k0 + wc8);
      *(s8vec*)&Wsm[r * G2_LDB + wc8] = v;
    }
    #pragma unroll
    for (int u = 0; u < 2; u++) {  // B: 32 k x 64 n, transposed write
      const int kl = u * 16 + kgq * 4;
      float f0 = 0.f, f1 = 0.f, f2v = 0.f, f3 = 0.f;
      const size_t gb = (size_t)(k0 + kl) * D_DIM + n0 + bn;
      if (k0 + kl + 0 < M_DIM) f0  = Bm[gb];
      if (k0 + kl + 1 < M_DIM) f1  = Bm[gb + D_DIM];
      if (k0 + kl + 2 < M_DIM) f2v = Bm[gb + 2 * (size_t)D_DIM];
      if (k0 + kl + 3 < M_DIM) f3  = Bm[gb + 3 * (size_t)D_DIM];
      ushort4 pk; pk.x = f2bf(f0); pk.y = f2bf(f1); pk.z = f2bf(f2v); pk.w = f2bf(f3);
      *(ushort4*)&Bt[bn * G2_LDB + kl] = pk;
    }
    __syncthreads();
    bf16x8 bfr[4];
    #pragma unroll
    for (int ni = 0; ni < 4; ni++)
      bfr[ni] = *(const bf16x8*)&Bt[(ni * 16 + lr) * G2_LDB + kq * 8];
    #pragma unroll
    for (int mi = 0; mi < 4; mi++) {
      const bf16x8 af = *(const bf16x8*)&Wsm[(wid * 64 + mi * 16 + lr) * G2_LDB + kq * 8];
      #pragma unroll
      for (int ni = 0; ni < 4; ni++)
        acc[mi][ni] = __builtin_amdgcn_mfma_f32_16x16x32_bf16(af, bfr[ni], acc[mi][ni], 0, 0, 0);
    }
  }
  #pragma unroll
  for (int mi = 0; mi < 4; mi++) {
    const int row0 = wid * 64 + mi * 16 + kq * 4;
    #pragma unroll
    for (int ni = 0; ni < 4; ni++) {
      const int col = n0 + ni * 16 + lr;
      #pragma unroll
      for (int j = 0; j < 4; j++)
        C[(size_t)(row0 + j) * D_DIM + col] = acc[mi][ni][j];
    }
  }
}

// ---------------- launch ----------------
extern "C" void kernel_launch(void* const* d_in, const int* in_sizes, int n_in,
                              void* d_out, int out_size, void* d_ws, size_t ws_size,
                              hipStream_t stream) {
  const float* feature = (const float*)d_in[0];   // [256][32768]
  const float* memory  = (const float*)d_in[1];   // [2000][32768]
  float* out_feat = (float*)d_out;                         // [256][32768]
  float* out_w = out_feat + (size_t)B_DIM * D_DIM;         // [256][2000]

  char* ws = (char*)d_ws;
  float* S   = (float*)ws;                        // [256][2048] fp32   (2 MB)
  float* rnf = (float*)(ws + 2097152);            // [256]
  float* rnm = (float*)(ws + 2098176);            // [2048]
  unsigned short* Wbf = (unsigned short*)(ws + 2106368);   // [256][2048] bf16 (1 MB)

  const int s_elems = B_DIM * M_PAD;
  zero_kernel<<<(s_elems + 255) / 256, 256, 0, stream>>>(S, s_elems);
  rownorm_kernel<<<B_DIM, 256, 0, stream>>>(feature, rnf);
  rownorm_kernel<<<M_DIM, 256, 0, stream>>>(memory, rnm);
  gemm1_kernel<<<dim3(32, 16), 256, 0, stream>>>(feature, memory, S);
  softmax_kernel<<<B_DIM, 256, 0, stream>>>(S, rnf, rnm, out_w, Wbf);
  gemm2_kernel<<<D_DIM / 64, 256, 0, stream>>>(Wbf, memory, out_feat);
}

// Round 2
// 563.002 us; speedup vs baseline: 1.1866x; 1.1866x over previous
//
#include <hip/hip_runtime.h>
#include <math.h>

// MemoryUnit: fn=l2norm(feature), mn=l2norm(memory), S=fn.mn^T -> softmax ->
// hardshrink(0.0005) -> softmax -> w ; mem_feat = w @ memory.
// Round 2: single fp32 pass per input (prep converts to bf16 + row norms),
// bf16-only GEMM staging (16B vector loads, BK=64), atomic-free split-K via
// Spart partials reduced in the softmax kernel.

#define D_DIM 32768
#define B_DIM 256
#define M_DIM 2000
#define M_PAD 2048
#define NSPLIT 16
#define LAM 0.0005f
#define LDA 72   // LDS row stride in ushorts: 144 B, 16B-aligned, bank step 4 -> 2-way max

typedef __attribute__((ext_vector_type(8))) short bf16x8;   // 8 bf16 = 4 VGPR
typedef __attribute__((ext_vector_type(4))) float f32x4;

__device__ __forceinline__ unsigned short f2bf(float f) {
  union { float f; unsigned u; } v; v.f = f;
  unsigned r = v.u + 0x7FFFu + ((v.u >> 16) & 1u);  // RNE
  return (unsigned short)(r >> 16);
}

// ---------------- prep: fp32 row -> bf16 row + 1/max(||x||,eps) ----------------
__global__ __launch_bounds__(256) void prep_kernel(const float* __restrict__ src,
                                                   unsigned short* __restrict__ dst,
                                                   float* __restrict__ rn_inv) {
  const size_t row = blockIdx.x;
  const int t = threadIdx.x;
  const float4* p = (const float4*)(src + row * (size_t)D_DIM);
  ushort4* q = (ushort4*)(dst + row * (size_t)D_DIM);
  float s = 0.f;
  for (int i = t; i < D_DIM / 4; i += 256) {
    float4 v = p[i];
    s = fmaf(v.x, v.x, s); s = fmaf(v.y, v.y, s);
    s = fmaf(v.z, v.z, s); s = fmaf(v.w, v.w, s);
    ushort4 b; b.x = f2bf(v.x); b.y = f2bf(v.y); b.z = f2bf(v.z); b.w = f2bf(v.w);
    q[i] = b;
  }
  #pragma unroll
  for (int off = 32; off > 0; off >>= 1) s += __shfl_down(s, off, 64);
  __shared__ float partial[4];
  if ((t & 63) == 0) partial[t >> 6] = s;
  __syncthreads();
  if (t == 0) {
    float tt = partial[0] + partial[1] + partial[2] + partial[3];
    rn_inv[row] = 1.0f / fmaxf(sqrtf(tt), 1e-12f);
  }
}

// ---------------- GEMM1: Spart[split][b][m] = F16[b][:] . Mem16[m][:] over k-slab ----
// BM=256 (all rows), BN=64, BK=64, split-K=16 (grid 32x16), plain stores.
__global__ __launch_bounds__(256) void gemm1_kernel(const unsigned short* __restrict__ A,
                                                    const unsigned short* __restrict__ Bm,
                                                    float* __restrict__ Spart) {
  __shared__ __align__(16) unsigned short Asm[256 * LDA];  // 36 KB
  __shared__ __align__(16) unsigned short Bsm[64 * LDA];   // 9 KB
  const int t = threadIdx.x;
  const int n0 = blockIdx.x * 64;
  const int kbase = blockIdx.y * (D_DIM / NSPLIT);
  const int wid = t >> 6, lane = t & 63;
  const int lr = lane & 15, kq = lane >> 4;
  const int sr = t >> 3;        // staging row base 0..31
  const int sc = (t & 7) * 8;   // staging ushort col (8 lanes x 16B = 128B contig)

  f32x4 acc[4][4] = {};

  for (int kk = 0; kk < D_DIM / NSPLIT; kk += 64) {
    const size_t kg = (size_t)(kbase + kk + sc);
    __syncthreads();
    #pragma unroll
    for (int i = 0; i < 8; i++) {            // A: 256 rows x 64 k
      const int r = sr + 32 * i;
      const bf16x8 v = *(const bf16x8*)(A + (size_t)r * D_DIM + kg);
      *(bf16x8*)&Asm[r * LDA + sc] = v;
    }
    #pragma unroll
    for (int i = 0; i < 2; i++) {            // B: 64 rows x 64 k (rows 2000..2047 junk, unused)
      const int r = sr + 32 * i;
      const bf16x8 v = *(const bf16x8*)(Bm + (size_t)(n0 + r) * D_DIM + kg);
      *(bf16x8*)&Bsm[r * LDA + sc] = v;
    }
    __syncthreads();
    bf16x8 bfr[4][2];
    #pragma unroll
    for (int ni = 0; ni < 4; ni++)
      #pragma unroll
      for (int h = 0; h < 2; h++)
        bfr[ni][h] = *(const bf16x8*)&Bsm[(ni * 16 + lr) * LDA + h * 32 + kq * 8];
    #pragma unroll
    for (int mi = 0; mi < 4; mi++) {
      #pragma unroll
      for (int h = 0; h < 2; h++) {
        const bf16x8 af = *(const bf16x8*)&Asm[(wid * 64 + mi * 16 + lr) * LDA + h * 32 + kq * 8];
        #pragma unroll
        for (int ni = 0; ni < 4; ni++)
          acc[mi][ni] = __builtin_amdgcn_mfma_f32_16x16x32_bf16(af, bfr[ni][h], acc[mi][ni], 0, 0, 0);
      }
    }
  }
  // C/D layout: col=lane&15, row=(lane>>4)*4+j  (verified round 1)
  float* Sp = Spart + (size_t)blockIdx.y * (B_DIM * M_PAD);
  #pragma unroll
  for (int mi = 0; mi < 4; mi++) {
    const int row0 = wid * 64 + mi * 16 + kq * 4;
    #pragma unroll
    for (int ni = 0; ni < 4; ni++) {
      const int col = n0 + ni * 16 + lr;
      #pragma unroll
      for (int j = 0; j < 4; j++)
        Sp[(size_t)(row0 + j) * M_PAD + col] = acc[mi][ni][j];
    }
  }
}

// ---------------- softmax: reduce splits -> scale -> softmax -> shrink -> softmax ----
__device__ __forceinline__ float block_reduce(float x, bool is_max, float* red,
                                              int wid, int lane) {
  #pragma unroll
  for (int off = 32; off > 0; off >>= 1) {
    float o = __shfl_down(x, off, 64);
    x = is_max ? fmaxf(x, o) : (x + o);
  }
  __syncthreads();
  if (lane == 0) red[wid] = x;
  __syncthreads();
  return is_max ? fmaxf(fmaxf(red[0], red[1]), fmaxf(red[2], red[3]))
                : (red[0] + red[1] + red[2] + red[3]);
}

__global__ __launch_bounds__(256) void softmax_kernel(const float* __restrict__ Spart,
                                                      const float* __restrict__ rnf,
                                                      const float* __restrict__ rnm,
                                                      float* __restrict__ wout,
                                                      unsigned short* __restrict__ wbf) {
  const int b = blockIdx.x;
  const int t = threadIdx.x;
  const int wid = t >> 6, lane = t & 63;
  const float sf = rnf[b];
  __shared__ float red[4];

  float v[8];
  #pragma unroll
  for (int i = 0; i < 8; i++) {
    const int m = t + 256 * i;
    float a = 0.f;
    #pragma unroll
    for (int s = 0; s < NSPLIT; s++)
      a += Spart[(size_t)s * (B_DIM * M_PAD) + (size_t)b * M_PAD + m];
    v[i] = (m < M_DIM) ? a * (sf * rnm[m]) : -INFINITY;
  }
  float mx = v[0];
  #pragma unroll
  for (int i = 1; i < 8; i++) mx = fmaxf(mx, v[i]);
  mx = block_reduce(mx, true, red, wid, lane);

  float e[8]; float sum = 0.f;
  #pragma unroll
  for (int i = 0; i < 8; i++) { e[i] = expf(v[i] - mx); sum += e[i]; }
  sum = block_reduce(sum, false, red, wid, lane);
  const float inv = 1.f / sum;

  float s2[8];
  #pragma unroll
  for (int i = 0; i < 8; i++) {
    float w1 = e[i] * inv;
    s2[i] = (w1 > LAM) ? w1 : 0.f;
  }
  float mx2 = 0.f;
  #pragma unroll
  for (int i = 0; i < 8; i++) mx2 = fmaxf(mx2, s2[i]);
  mx2 = block_reduce(mx2, true, red, wid, lane);

  float e2[8]; float sum2 = 0.f;
  #pragma unroll
  for (int i = 0; i < 8; i++) {
    const int m = t + 256 * i;
    e2[i] = (m < M_DIM) ? expf(s2[i] - mx2) : 0.f;
    sum2 += e2[i];
  }
  sum2 = block_reduce(sum2, false, red, wid, lane);
  const float inv2 = 1.f / sum2;

  #pragma unroll
  for (int i = 0; i < 8; i++) {
    const int m = t + 256 * i;
    const float w2 = e2[i] * inv2;
    if (m < M_DIM) wout[(size_t)b * M_DIM + m] = w2;
    wbf[(size_t)b * M_PAD + m] = f2bf(w2);   // padded cols get exact 0
  }
}

// ---------------- GEMM2: C[b][n] = sum_k Wbf[b][k] * Mem16[k][n] ----------------
// BM=256, BN=64, BK=64, grid 512 n-tiles; B transposed into LDS during staging.
__global__ __launch_bounds__(256) void gemm2_kernel(const unsigned short* __restrict__ W,
                                                    const unsigned short* __restrict__ Bm,
                                                    float* __restrict__ C) {
  __shared__ __align__(16) unsigned short Wsm[256 * LDA];  // 36 KB
  __shared__ __align__(16) unsigned short Bt[64 * LDA];    // 9 KB, [n][k] k-contig
  const int t = threadIdx.x;
  const int n0 = blockIdx.x * 64;
  const int wid = t >> 6, lane = t & 63;
  const int lr = lane & 15, kq = lane >> 4;
  const int sr = t >> 3, sc = (t & 7) * 8;   // W staging
  const int bk = t >> 4;                     // B staging k-row base 0..15
  const int bnc = (t & 15) * 4;              // B staging n col (x4)

  f32x4 acc[4][4] = {};

  for (int k0 = 0; k0 < M_PAD; k0 += 64) {
    __syncthreads();
    #pragma unroll
    for (int i = 0; i < 8; i++) {            // W: 256 rows x 64 k (bf16)
      const int r = sr + 32 * i;
      const bf16x8 v = *(const bf16x8*)(W + (size_t)r * M_PAD + k0 + sc);
      *(bf16x8*)&Wsm[r * LDA + sc] = v;
    }
    #pragma unroll
    for (int i = 0; i < 4; i++) {            // B: 64 k x 64 n, transposed write
      const int kl = bk + 16 * i;
      const ushort4 v = *(const ushort4*)(Bm + (size_t)(k0 + kl) * D_DIM + n0 + bnc);
      Bt[(bnc + 0) * LDA + kl] = v.x;
      Bt[(bnc + 1) * LDA + kl] = v.y;
      Bt[(bnc + 2) * LDA + kl] = v.z;
      Bt[(bnc + 3) * LDA + kl] = v.w;
    }
    __syncthreads();
    bf16x8 bfr[4][2];
    #pragma unroll
    for (int ni = 0; ni < 4; ni++)
      #pragma unroll
      for (int h = 0; h < 2; h++)
        bfr[ni][h] = *(const bf16x8*)&Bt[(ni * 16 + lr) * LDA + h * 32 + kq * 8];
    #pragma unroll
    for (int mi = 0; mi < 4; mi++) {
      #pragma unroll
      for (int h = 0; h < 2; h++) {
        const bf16x8 af = *(const bf16x8*)&Wsm[(wid * 64 + mi * 16 + lr) * LDA + h * 32 + kq * 8];
        #pragma unroll
        for (int ni = 0; ni < 4; ni++)
          acc[mi][ni] = __builtin_amdgcn_mfma_f32_16x16x32_bf16(af, bfr[ni][h], acc[mi][ni], 0, 0, 0);
      }
    }
  }
  #pragma unroll
  for (int mi = 0; mi < 4; mi++) {
    const int row0 = wid * 64 + mi * 16 + kq * 4;
    #pragma unroll
    for (int ni = 0; ni < 4; ni++) {
      const int col = n0 + ni * 16 + lr;
      #pragma unroll
      for (int j = 0; j < 4; j++)
        C[(size_t)(row0 + j) * D_DIM + col] = acc[mi][ni][j];
    }
  }
}

// ---------------- launch ----------------
extern "C" void kernel_launch(void* const* d_in, const int* in_sizes, int n_in,
                              void* d_out, int out_size, void* d_ws, size_t ws_size,
                              hipStream_t stream) {
  const float* feature = (const float*)d_in[0];   // [256][32768]
  const float* memory  = (const float*)d_in[1];   // [2000][32768]
  float* out_feat = (float*)d_out;                         // [256][32768]
  float* out_w = out_feat + (size_t)B_DIM * D_DIM;         // [256][2000]

  char* ws = (char*)d_ws;
  unsigned short* Mem16 = (unsigned short*)ws;                        // [2048][32768] bf16 (rows 2000+ unwritten junk, never used)
  unsigned short* F16   = (unsigned short*)(ws + 134217728);          // [256][32768] bf16
  float* Spart          = (float*)(ws + 150994944);                   // [16][256][2048] fp32
  unsigned short* Wbf   = (unsigned short*)(ws + 184549376);          // [256][2048] bf16
  float* rnm            = (float*)(ws + 185597952);                   // [2048]
  float* rnf            = (float*)(ws + 185606144);                   // [256]

  prep_kernel<<<M_DIM, 256, 0, stream>>>(memory, Mem16, rnm);
  prep_kernel<<<B_DIM, 256, 0, stream>>>(feature, F16, rnf);
  gemm1_kernel<<<dim3(32, NSPLIT), 256, 0, stream>>>(F16, Mem16, Spart);
  softmax_kernel<<<B_DIM, 256, 0, stream>>>(Spart, rnf, rnm, out_w, Wbf);
  gemm2_kernel<<<D_DIM / 64, 256, 0, stream>>>(Wbf, Mem16, out_feat);
}